// Round 1
// 5965.258 us; speedup vs baseline: 1.1953x; 1.1953x over previous
//
#include <hip/hip_runtime.h>

// ---------------- types / helpers ----------------
typedef short bhalf8 __attribute__((ext_vector_type(8)));   // 8 bf16 in 4 VGPRs
typedef float f32x4  __attribute__((ext_vector_type(4)));

__device__ __forceinline__ unsigned short f2bf(float f) {
    unsigned int u = __builtin_bit_cast(unsigned int, f);
    u = (u + 0x7fffu + ((u >> 16) & 1u)) >> 16;   // RNE
    return (unsigned short)u;
}
__device__ __forceinline__ float bf2f(unsigned short h) {
    unsigned int u = ((unsigned int)h) << 16;
    return __builtin_bit_cast(float, u);
}

#define SEQ   512
#define BATCH 64
#define HID   1024
#define EMBD  1024
#define VOCAB 32000
#define N3H   3072
#define NBLK  64
#define NSUB  8

// ---------------- fp32 -> bf16 convert (4 elems/thread) ----------------
__global__ void k_cvt4(const float4* __restrict__ in, ushort4* __restrict__ out, int n4) {
    int i = blockIdx.x * blockDim.x + threadIdx.x;
    if (i < n4) {
        float4 v = in[i];
        ushort4 o;
        o.x = f2bf(v.x); o.y = f2bf(v.y); o.z = f2bf(v.z); o.w = f2bf(v.w);
        out[i] = o;
    }
}

// ---------------- gi GEMM: (32768 x 1024) gathered-A  @  W_ih^T -> bf16 ----------------
// block = 256 thr (4 waves). wave tile = m(4x16) x n64: 16 accs, B-frags reused 4x.
__global__ __launch_bounds__(256)
void k_gi(const int* __restrict__ tok, const unsigned short* __restrict__ embb,
          const unsigned short* __restrict__ wih, unsigned short* __restrict__ gi) {
    int nb = blockIdx.x;            // 0..47
    int mb = blockIdx.y;            // 0..127
    int w    = threadIdx.x >> 6;
    int lane = threadIdx.x & 63;
    int q = lane >> 4, l = lane & 15;
    int m0 = mb * 256 + w * 16;     // m-tiles at m0 + 64*i, i=0..3
    int n0 = nb * 64;

    const unsigned short* ap[4];
#pragma unroll
    for (int i = 0; i < 4; ++i)
        ap[i] = embb + (size_t)tok[m0 + 64 * i + l] * EMBD + q * 8;

    const unsigned short* bp[4];
#pragma unroll
    for (int j = 0; j < 4; ++j)
        bp[j] = wih + (size_t)(n0 + 16 * j + l) * EMBD + q * 8;

    f32x4 acc[4][4];
#pragma unroll
    for (int i = 0; i < 4; ++i)
#pragma unroll
        for (int j = 0; j < 4; ++j)
            acc[i][j] = (f32x4){0.f, 0.f, 0.f, 0.f};

#pragma unroll 2
    for (int kk = 0; kk < 32; ++kk) {
        int ko = kk * 32;
        bhalf8 bv[4], av[4];
#pragma unroll
        for (int j = 0; j < 4; ++j) bv[j] = *(const bhalf8*)(bp[j] + ko);
#pragma unroll
        for (int i = 0; i < 4; ++i) av[i] = *(const bhalf8*)(ap[i] + ko);
#pragma unroll
        for (int i = 0; i < 4; ++i)
#pragma unroll
            for (int j = 0; j < 4; ++j)
                acc[i][j] = __builtin_amdgcn_mfma_f32_16x16x32_bf16(av[i], bv[j], acc[i][j], 0, 0, 0);
    }
    // C/D layout: row(m) = q*4+reg, col(n) = l
#pragma unroll
    for (int i = 0; i < 4; ++i)
#pragma unroll
        for (int r = 0; r < 4; ++r) {
            size_t mrow = (size_t)(m0 + 64 * i + q * 4 + r) * N3H + n0;
            gi[mrow +  0 + l] = f2bf(acc[i][0][r]);
            gi[mrow + 16 + l] = f2bf(acc[i][1][r]);
            gi[mrow + 32 + l] = f2bf(acc[i][2][r]);
            gi[mrow + 48 + l] = f2bf(acc[i][3][r]);
        }
}

// ---------------- epoch barrier: zero wbl2, one inv per BLOCK ----------------
// All cross-block h data is written with write-through RELAXED agent atomic
// stores (each is individually visible at the agent coherence point once its
// vmcnt retires), so ARRIVE needs no buffer_wbl2: __syncthreads drains vmcnt,
// then a RELAXED fetch_add signals. Arrival is a 2-level tree (NSUB
// sub-counters x NBLK/NSUB blocks, separate cache lines) to cut same-line RMW
// serialization. DEPART does ONE agent-acquire (buffer_inv) per block
// (thread 0); the closing __syncthreads orders it before all waves' h loads
// (1 block = 1 CU, so one inv covers the CU's L1 and this XCD's L2).
__device__ __forceinline__ void gbar(int* cnt, int* cnt2, int e, int sg) {
    __syncthreads();   // drains vmcnt -> this block's write-through h stores are agent-visible
    if (threadIdx.x == 0) {
        if (__hip_atomic_fetch_add(cnt2 + (size_t)e * NSUB + sg, 1,
                                   __ATOMIC_RELAXED, __HIP_MEMORY_SCOPE_AGENT) == NBLK / NSUB - 1)
            __hip_atomic_fetch_add(cnt + e, 1, __ATOMIC_RELAXED, __HIP_MEMORY_SCOPE_AGENT);
        while (__hip_atomic_load(cnt + e, __ATOMIC_RELAXED, __HIP_MEMORY_SCOPE_AGENT) < NSUB)
            __builtin_amdgcn_s_sleep(1);
        int v = __hip_atomic_load(cnt + e, __ATOMIC_ACQUIRE, __HIP_MEMORY_SCOPE_AGENT);
        if (v < NSUB) __builtin_amdgcn_s_sleep(127);   // never taken; keeps acquire alive
    }
    __syncthreads();
}

// ---------------- persistent recurrence ----------------
// 64 blocks = 64 unit-groups; block = 256 thr (4 waves = 4 batch-quarters,
// 16 batches each). Same 256 total waves / per-wave MFMA work as before, but
// half the barrier participants.
__global__ __launch_bounds__(256, 1)
void k_rec(const float* __restrict__ W_hh,
           const unsigned short* __restrict__ gib,
           const float* __restrict__ bih, const float* __restrict__ bhh,
           const float* __restrict__ hidden,
           float* __restrict__ out,
           unsigned short* hbuf,          // bf16 [2][64*1024]
           int* cnt,                      // [SEQ+1], zeroed (root)
           int* cnt2) {                   // [SEQ+1][NSUB], zeroed (tree leaves)
    __shared__ unsigned short sh[32768];  // 64 KB: gates r,z for this unit group

    const int tid  = threadIdx.x;
    const int w    = tid >> 6;            // batch quarter 0..3
    const int lane = tid & 63;
    const int q = lane >> 4, l = lane & 15;
    const int G  = blockIdx.x;            // unit group 0..63
    const int sg = blockIdx.x & (NSUB - 1);
    const int m0 = w * 16;
    const int u0 = G * 16 + l;

    // ---- prologue: r,z gate fragments -> LDS (fragment order: [g][kk][lane]*16B) ----
    for (int i = 0; i < 16; ++i) {
        int c  = i * 256 + tid;           // 0..4095
        int g  = c >> 11;                 // 0..1
        int kk = (c >> 6) & 31;
        int ln = c & 63;
        int uu = ln & 15, qq = ln >> 4;
        const float* src = W_hh + (size_t)(g * 1024 + G * 16 + uu) * 1024 + kk * 32 + qq * 8;
        float4 f0 = *(const float4*)src;
        float4 f1 = *(const float4*)(src + 4);
        ushort4 o0, o1;
        o0.x = f2bf(f0.x); o0.y = f2bf(f0.y); o0.z = f2bf(f0.z); o0.w = f2bf(f0.w);
        o1.x = f2bf(f1.x); o1.y = f2bf(f1.y); o1.z = f2bf(f1.z); o1.w = f2bf(f1.w);
        *(ushort4*)&sh[c * 8]     = o0;
        *(ushort4*)&sh[c * 8 + 4] = o1;
    }

    // ---- n-gate fragments in registers ----
    bhalf8 bn[32];
#pragma unroll
    for (int kk = 0; kk < 32; ++kk) {
        const float* src = W_hh + (size_t)(2048 + u0) * 1024 + kk * 32 + q * 8;
        float4 f0 = *(const float4*)src;
        float4 f1 = *(const float4*)(src + 4);
        bhalf8 v;
        v[0] = (short)f2bf(f0.x); v[1] = (short)f2bf(f0.y);
        v[2] = (short)f2bf(f0.z); v[3] = (short)f2bf(f0.w);
        v[4] = (short)f2bf(f1.x); v[5] = (short)f2bf(f1.y);
        v[6] = (short)f2bf(f1.z); v[7] = (short)f2bf(f1.w);
        bn[kk] = v;
    }

    // ---- h0 init + biases (h exchanged via write-through relaxed agent stores) ----
    float hp[4];
#pragma unroll
    for (int r = 0; r < 4; ++r) {
        int b = m0 + q * 4 + r;
        float hv = hidden[(size_t)b * HID + u0];
        hp[r] = hv;
        __hip_atomic_store(hbuf + (size_t)b * HID + u0, f2bf(hv),
                           __ATOMIC_RELAXED, __HIP_MEMORY_SCOPE_AGENT);
    }
    float bir = bih[u0], biz = bih[HID + u0], bin = bih[2 * HID + u0];
    float bhr = bhh[u0], bhz = bhh[HID + u0], bhn = bhh[2 * HID + u0];

    // ---- gi prefetch for t=0 (b_ih folded in) ----
    float i_r[4], i_z[4], i_n[4];
#pragma unroll
    for (int r = 0; r < 4; ++r) {
        const unsigned short* gp = gib + (size_t)(m0 + q * 4 + r) * N3H + u0;
        i_r[r] = bf2f(gp[0])       + bir;
        i_z[r] = bf2f(gp[HID])     + biz;
        i_n[r] = bf2f(gp[2 * HID]) + bin;
    }

    gbar(cnt, cnt2, 0, sg);   // h0 visible everywhere

    for (int t = 0; t < SEQ; ++t) {
        const unsigned short* hc = hbuf + (size_t)(t & 1) * (BATCH * HID);
        unsigned short*       hn = hbuf + (size_t)((t + 1) & 1) * (BATCH * HID);

        // issue gi(t+1) loads at the TOP of the step: their HBM latency hides
        // under the k-loop, and they are long-retired by the next barrier's
        // vmcnt drain (instead of stalling it).
        unsigned short pr[4], pz[4], pn[4];
        if (t + 1 < SEQ) {
            const unsigned short* gt = gib + (size_t)(t + 1) * (BATCH * N3H);
#pragma unroll
            for (int r = 0; r < 4; ++r) {
                const unsigned short* gp = gt + (size_t)(m0 + q * 4 + r) * N3H + u0;
                pr[r] = gp[0]; pz[r] = gp[HID]; pn[r] = gp[2 * HID];
            }
        }

        const unsigned short* hA = hc + (size_t)(m0 + l) * HID + q * 8;
        f32x4 ar = {0.f, 0.f, 0.f, 0.f}, az = ar, an = ar;
#pragma unroll
        for (int kk = 0; kk < 32; ++kk) {
            bhalf8 a   = *(const bhalf8*)(hA + kk * 32);
            bhalf8 brf = *(const bhalf8*)&sh[kk * 512 + lane * 8];
            bhalf8 bzf = *(const bhalf8*)&sh[16384 + kk * 512 + lane * 8];
            ar = __builtin_amdgcn_mfma_f32_16x16x32_bf16(a, brf, ar, 0, 0, 0);
            az = __builtin_amdgcn_mfma_f32_16x16x32_bf16(a, bzf, az, 0, 0, 0);
            an = __builtin_amdgcn_mfma_f32_16x16x32_bf16(a, bn[kk], an, 0, 0, 0);
        }

        float osv[4];
#pragma unroll
        for (int r = 0; r < 4; ++r) {
            int b = m0 + q * 4 + r;
            float rr = 1.f / (1.f + __expf(-(i_r[r] + ar[r] + bhr)));
            float zz = 1.f / (1.f + __expf(-(i_z[r] + az[r] + bhz)));
            float nn = tanhf(i_n[r] + rr * (an[r] + bhn));
            float hv = (1.f - zz) * nn + zz * hp[r];
            hp[r] = hv;
            osv[r] = hv;
            // write-through: agent-visible once vmcnt retires -> no wbl2 at barrier
            __hip_atomic_store(hn + (size_t)b * HID + u0, f2bf(hv),
                               __ATOMIC_RELAXED, __HIP_MEMORY_SCOPE_AGENT);
        }

        if (t + 1 < SEQ) {
#pragma unroll
            for (int r = 0; r < 4; ++r) {   // fold bias; loads retired long ago
                i_r[r] = bf2f(pr[r]) + bir;
                i_z[r] = bf2f(pz[r]) + biz;
                i_n[r] = bf2f(pn[r]) + bin;
            }
            gbar(cnt, cnt2, t + 1, sg);
        }

        // out stores AFTER the barrier: drain under the next k-loop instead of
        // sitting on the barrier's vmcnt(0) critical path. Never re-read.
        float* ot = out + (size_t)t * (BATCH * HID);
#pragma unroll
        for (int r = 0; r < 4; ++r)
            __builtin_nontemporal_store(osv[r], &ot[(size_t)(m0 + q * 4 + r) * HID + u0]);
    }
}

// ---------------- launch ----------------
extern "C" void kernel_launch(void* const* d_in, const int* in_sizes, int n_in,
                              void* d_out, int out_size, void* d_ws, size_t ws_size,
                              hipStream_t stream) {
    (void)in_sizes; (void)n_in; (void)out_size;
    const int*   input  = (const int*)  d_in[0];
    const float* hidden = (const float*)d_in[2];
    const float* emb    = (const float*)d_in[3];
    const float* W_ih   = (const float*)d_in[4];
    const float* W_hh   = (const float*)d_in[5];
    const float* b_ih   = (const float*)d_in[6];
    const float* b_hh   = (const float*)d_in[7];
    float* out = (float*)d_out;

    // workspace layout (bytes)
    const size_t EMB_BF  = 0;                                   // 65,536,000
    const size_t WIH_BF  = EMB_BF + (size_t)VOCAB * EMBD * 2;   // +6,291,456
    const size_t GI_OFF  = WIH_BF + (size_t)N3H * EMBD * 2;     // +201,326,592
    const size_t H_OFF   = GI_OFF + (size_t)SEQ * BATCH * N3H * 2;
    const size_t CNT_OFF = H_OFF + (size_t)2 * BATCH * HID * 2;
    const size_t CNT2_OFF = CNT_OFF + (size_t)(SEQ + 1) * 4;
    const size_t NEED    = CNT2_OFF + (size_t)(SEQ + 1) * NSUB * 4;
    if (ws_size < NEED) return;

    char* ws = (char*)d_ws;
    unsigned short* embb = (unsigned short*)(ws + EMB_BF);
    unsigned short* wihb = (unsigned short*)(ws + WIH_BF);
    unsigned short* gib  = (unsigned short*)(ws + GI_OFF);
    unsigned short* hbuf = (unsigned short*)(ws + H_OFF);
    int*            cnt  = (int*)(ws + CNT_OFF);
    int*            cnt2 = (int*)(ws + CNT2_OFF);

    hipMemsetAsync(cnt, 0, (size_t)(SEQ + 1) * 4 * (1 + NSUB), stream);

    {
        int n4 = VOCAB * EMBD / 4;
        k_cvt4<<<(n4 + 255) / 256, 256, 0, stream>>>((const float4*)emb, (ushort4*)embb, n4);
    }
    {
        int n4 = N3H * EMBD / 4;
        k_cvt4<<<(n4 + 255) / 256, 256, 0, stream>>>((const float4*)W_ih, (ushort4*)wihb, n4);
    }

    // input-side GEMM for all timesteps
    k_gi<<<dim3(48, 128), 256, 0, stream>>>(input, embb, wihb, gib);

    // persistent recurrence: 64 blocks (64 KB LDS each -> all co-resident)
    k_rec<<<NBLK, 256, 0, stream>>>(W_hh, gib, b_ih, b_hh, hidden, out, hbuf, cnt, cnt2);
}

// Round 2
// 4278.584 us; speedup vs baseline: 1.6665x; 1.3942x over previous
//
#include <hip/hip_runtime.h>

// ---------------- types / helpers ----------------
typedef short bhalf8 __attribute__((ext_vector_type(8)));   // 8 bf16 in 4 VGPRs
typedef float f32x4  __attribute__((ext_vector_type(4)));

__device__ __forceinline__ unsigned short f2bf(float f) {
    unsigned int u = __builtin_bit_cast(unsigned int, f);
    u = (u + 0x7fffu + ((u >> 16) & 1u)) >> 16;   // RNE
    return (unsigned short)u;
}
__device__ __forceinline__ float bf2f(unsigned short h) {
    unsigned int u = ((unsigned int)h) << 16;
    return __builtin_bit_cast(float, u);
}

// L2-bypass 16B load (sc0 sc1 -> reads the agent coherence point / MALL).
// hbuf is ONLY ever accessed with bypass ops, so no cache level ever holds a
// stale copy and no buffer_inv is needed at the barrier.
__device__ __forceinline__ bhalf8 ldg16_bypass(const unsigned short* p) {
    bhalf8 r;
    asm volatile("global_load_dwordx4 %0, %1, off sc0 sc1"
                 : "=v"(r) : "v"(p));
    return r;
}

// counted vmcnt wait; sched_barrier stops hipcc hoisting MFMAs above it (rule #18)
#define VWAIT(N)                                                     \
    do {                                                             \
        asm volatile("s_waitcnt vmcnt(" #N ")" ::: "memory");        \
        __builtin_amdgcn_sched_barrier(0);                           \
    } while (0)

#define SEQ   512
#define BATCH 64
#define HID   1024
#define EMBD  1024
#define VOCAB 32000
#define N3H   3072
#define NBLK  64
#define FLAGSTRIDE 32   // ints; 128B line per flag

// ---------------- fp32 -> bf16 convert (4 elems/thread) ----------------
__global__ void k_cvt4(const float4* __restrict__ in, ushort4* __restrict__ out, int n4) {
    int i = blockIdx.x * blockDim.x + threadIdx.x;
    if (i < n4) {
        float4 v = in[i];
        ushort4 o;
        o.x = f2bf(v.x); o.y = f2bf(v.y); o.z = f2bf(v.z); o.w = f2bf(v.w);
        out[i] = o;
    }
}

// ---------------- gi GEMM: (32768 x 1024) gathered-A  @  W_ih^T -> bf16 ----------------
__global__ __launch_bounds__(256)
void k_gi(const int* __restrict__ tok, const unsigned short* __restrict__ embb,
          const unsigned short* __restrict__ wih, unsigned short* __restrict__ gi) {
    int nb = blockIdx.x;            // 0..47
    int mb = blockIdx.y;            // 0..127
    int w    = threadIdx.x >> 6;
    int lane = threadIdx.x & 63;
    int q = lane >> 4, l = lane & 15;
    int m0 = mb * 256 + w * 16;
    int n0 = nb * 64;

    const unsigned short* ap[4];
#pragma unroll
    for (int i = 0; i < 4; ++i)
        ap[i] = embb + (size_t)tok[m0 + 64 * i + l] * EMBD + q * 8;

    const unsigned short* bp[4];
#pragma unroll
    for (int j = 0; j < 4; ++j)
        bp[j] = wih + (size_t)(n0 + 16 * j + l) * EMBD + q * 8;

    f32x4 acc[4][4];
#pragma unroll
    for (int i = 0; i < 4; ++i)
#pragma unroll
        for (int j = 0; j < 4; ++j)
            acc[i][j] = (f32x4){0.f, 0.f, 0.f, 0.f};

#pragma unroll 2
    for (int kk = 0; kk < 32; ++kk) {
        int ko = kk * 32;
        bhalf8 bv[4], av[4];
#pragma unroll
        for (int j = 0; j < 4; ++j) bv[j] = *(const bhalf8*)(bp[j] + ko);
#pragma unroll
        for (int i = 0; i < 4; ++i) av[i] = *(const bhalf8*)(ap[i] + ko);
#pragma unroll
        for (int i = 0; i < 4; ++i)
#pragma unroll
            for (int j = 0; j < 4; ++j)
                acc[i][j] = __builtin_amdgcn_mfma_f32_16x16x32_bf16(av[i], bv[j], acc[i][j], 0, 0, 0);
    }
#pragma unroll
    for (int i = 0; i < 4; ++i)
#pragma unroll
        for (int r = 0; r < 4; ++r) {
            size_t mrow = (size_t)(m0 + 64 * i + q * 4 + r) * N3H + n0;
            gi[mrow +  0 + l] = f2bf(acc[i][0][r]);
            gi[mrow + 16 + l] = f2bf(acc[i][1][r]);
            gi[mrow + 32 + l] = f2bf(acc[i][2][r]);
            gi[mrow + 48 + l] = f2bf(acc[i][3][r]);
        }
}

// ---------------- flag barrier: no RMW, no acquire-inv ----------------
// Arrive: __syncthreads drains vmcnt (h write-through stores are then at the
// agent coherence point), then thread 0 does ONE relaxed agent STORE of the
// epoch to this block's private flag line. Detect: wave 0's 64 lanes each
// poll one block's flag in parallel; done when __all(v >= e). No buffer_wbl2,
// no buffer_inv, no atomic RMW anywhere -> L2 stays warm for gi/W/out.
// Correct because hbuf is only ever accessed with L2-bypass (sc0 sc1) ops.
__device__ __forceinline__ void gbar(int* flags, int e) {
    __syncthreads();   // vmcnt(0): this block's h stores are agent-visible
    if (threadIdx.x == 0)
        __hip_atomic_store(flags + (size_t)blockIdx.x * FLAGSTRIDE, e,
                           __ATOMIC_RELAXED, __HIP_MEMORY_SCOPE_AGENT);
    if (threadIdx.x < 64) {
        for (;;) {
            int v = __hip_atomic_load(flags + (size_t)threadIdx.x * FLAGSTRIDE,
                                      __ATOMIC_RELAXED, __HIP_MEMORY_SCOPE_AGENT);
            if (__all(v >= e)) break;
            __builtin_amdgcn_s_sleep(1);
        }
    }
    __syncthreads();
}

// ---------------- persistent recurrence ----------------
// 64 blocks = 64 unit-groups; block = 256 thr (4 waves = 4 batch-quarters).
__global__ __launch_bounds__(256, 1)
void k_rec(const float* __restrict__ W_hh,
           const unsigned short* __restrict__ gib,
           const float* __restrict__ bih, const float* __restrict__ bhh,
           const float* __restrict__ hidden,
           float* __restrict__ out,
           unsigned short* hbuf,          // bf16 [2][64*1024], bypass-only
           int* flags) {                  // [NBLK*FLAGSTRIDE], zeroed
    __shared__ unsigned short sh[32768];  // 64 KB: gates r,z for this unit group

    const int tid  = threadIdx.x;
    const int w    = tid >> 6;            // batch quarter 0..3
    const int lane = tid & 63;
    const int q = lane >> 4, l = lane & 15;
    const int G  = blockIdx.x;            // unit group 0..63
    const int m0 = w * 16;
    const int u0 = G * 16 + l;

    // ---- prologue: r,z gate fragments -> LDS ----
    for (int i = 0; i < 16; ++i) {
        int c  = i * 256 + tid;           // 0..4095
        int g  = c >> 11;                 // 0..1
        int kk = (c >> 6) & 31;
        int ln = c & 63;
        int uu = ln & 15, qq = ln >> 4;
        const float* src = W_hh + (size_t)(g * 1024 + G * 16 + uu) * 1024 + kk * 32 + qq * 8;
        float4 f0 = *(const float4*)src;
        float4 f1 = *(const float4*)(src + 4);
        ushort4 o0, o1;
        o0.x = f2bf(f0.x); o0.y = f2bf(f0.y); o0.z = f2bf(f0.z); o0.w = f2bf(f0.w);
        o1.x = f2bf(f1.x); o1.y = f2bf(f1.y); o1.z = f2bf(f1.z); o1.w = f2bf(f1.w);
        *(ushort4*)&sh[c * 8]     = o0;
        *(ushort4*)&sh[c * 8 + 4] = o1;
    }

    // ---- n-gate fragments in registers ----
    bhalf8 bn[32];
#pragma unroll
    for (int kk = 0; kk < 32; ++kk) {
        const float* src = W_hh + (size_t)(2048 + u0) * 1024 + kk * 32 + q * 8;
        float4 f0 = *(const float4*)src;
        float4 f1 = *(const float4*)(src + 4);
        bhalf8 v;
        v[0] = (short)f2bf(f0.x); v[1] = (short)f2bf(f0.y);
        v[2] = (short)f2bf(f0.z); v[3] = (short)f2bf(f0.w);
        v[4] = (short)f2bf(f1.x); v[5] = (short)f2bf(f1.y);
        v[6] = (short)f2bf(f1.z); v[7] = (short)f2bf(f1.w);
        bn[kk] = v;
    }

    // ---- h0 init + biases (hbuf written write-through, bypass-only) ----
    float hp[4];
#pragma unroll
    for (int r = 0; r < 4; ++r) {
        int b = m0 + q * 4 + r;
        float hv = hidden[(size_t)b * HID + u0];
        hp[r] = hv;
        __hip_atomic_store(hbuf + (size_t)b * HID + u0, f2bf(hv),
                           __ATOMIC_RELAXED, __HIP_MEMORY_SCOPE_AGENT);
    }
    float bir = bih[u0], biz = bih[HID + u0], bin = bih[2 * HID + u0];
    float bhr = bhh[u0], bhz = bhh[HID + u0], bhn = bhh[2 * HID + u0];

    // ---- gi prefetch for t=0 (b_ih folded in) ----
    float i_r[4], i_z[4], i_n[4];
#pragma unroll
    for (int r = 0; r < 4; ++r) {
        const unsigned short* gp = gib + (size_t)(m0 + q * 4 + r) * N3H + u0;
        i_r[r] = bf2f(gp[0])       + bir;
        i_z[r] = bf2f(gp[HID])     + biz;
        i_n[r] = bf2f(gp[2 * HID]) + bin;
    }

    gbar(flags, 1);   // h0 visible everywhere

// h-load group: 8 bypass loads (issue only, no wait)
#define ISSUE8(AV, KB)                                                   \
    _Pragma("unroll")                                                    \
    for (int j = 0; j < 8; ++j) AV[j] = ldg16_bypass(hA + ((KB) + j) * 32);

// compute 8 k-slices consuming AV
#define COMPUTE8(AV, KB)                                                 \
    _Pragma("unroll")                                                    \
    for (int j = 0; j < 8; ++j) {                                        \
        int kk = (KB) + j;                                               \
        bhalf8 brf = *(const bhalf8*)&sh[kk * 512 + lane * 8];           \
        bhalf8 bzf = *(const bhalf8*)&sh[16384 + kk * 512 + lane * 8];   \
        ar = __builtin_amdgcn_mfma_f32_16x16x32_bf16(AV[j], brf, ar, 0, 0, 0); \
        az = __builtin_amdgcn_mfma_f32_16x16x32_bf16(AV[j], bzf, az, 0, 0, 0); \
        an = __builtin_amdgcn_mfma_f32_16x16x32_bf16(AV[j], bn[kk], an, 0, 0, 0); \
    }

    for (int t = 0; t < SEQ; ++t) {
        const unsigned short* hc = hbuf + (size_t)(t & 1) * (BATCH * HID);
        unsigned short*       hn = hbuf + (size_t)((t + 1) & 1) * (BATCH * HID);

        // gi(t+1) prefetch at top: HBM/L2 latency hides under the k-loop
        unsigned short pr[4], pz[4], pn[4];
        if (t + 1 < SEQ) {
            const unsigned short* gt = gib + (size_t)(t + 1) * (BATCH * N3H);
#pragma unroll
            for (int r = 0; r < 4; ++r) {
                const unsigned short* gp = gt + (size_t)(m0 + q * 4 + r) * N3H + u0;
                pr[r] = gp[0]; pz[r] = gp[HID]; pn[r] = gp[2 * HID];
            }
        }

        const unsigned short* hA = hc + (size_t)(m0 + l) * HID + q * 8;
        f32x4 ar = {0.f, 0.f, 0.f, 0.f}, az = ar, an = ar;

        // manually double-buffered bypass-load pipeline, counted vmcnt.
        // In-order vmcnt retirement + >=8 younger ops guarantee each waited
        // group is complete (gi prefetch loads only add older/interleaved ops).
        {
            bhalf8 ha[8], hb[8];
            ISSUE8(ha, 0)
            ISSUE8(hb, 8)
            VWAIT(8);
            COMPUTE8(ha, 0)
            ISSUE8(ha, 16)
            VWAIT(8);
            COMPUTE8(hb, 8)
            ISSUE8(hb, 24)
            VWAIT(8);
            COMPUTE8(ha, 16)
            VWAIT(0);
            COMPUTE8(hb, 24)
        }

        float osv[4];
#pragma unroll
        for (int r = 0; r < 4; ++r) {
            int b = m0 + q * 4 + r;
            float rr = 1.f / (1.f + __expf(-(i_r[r] + ar[r] + bhr)));
            float zz = 1.f / (1.f + __expf(-(i_z[r] + az[r] + bhz)));
            float nn = tanhf(i_n[r] + rr * (an[r] + bhn));
            float hv = (1.f - zz) * nn + zz * hp[r];
            hp[r] = hv;
            osv[r] = hv;
            if (t + 1 < SEQ)   // write-through: agent-visible once vmcnt retires
                __hip_atomic_store(hn + (size_t)b * HID + u0, f2bf(hv),
                                   __ATOMIC_RELAXED, __HIP_MEMORY_SCOPE_AGENT);
        }

        if (t + 1 < SEQ) {
#pragma unroll
            for (int r = 0; r < 4; ++r) {   // fold bias; loads retired long ago
                i_r[r] = bf2f(pr[r]) + bir;
                i_z[r] = bf2f(pz[r]) + biz;
                i_n[r] = bf2f(pn[r]) + bin;
            }
            gbar(flags, t + 2);
        }

        // out stores AFTER the barrier: drain under the next k-loop
        float* ot = out + (size_t)t * (BATCH * HID);
#pragma unroll
        for (int r = 0; r < 4; ++r)
            __builtin_nontemporal_store(osv[r], &ot[(size_t)(m0 + q * 4 + r) * HID + u0]);
    }
#undef ISSUE8
#undef COMPUTE8
}

// ---------------- launch ----------------
extern "C" void kernel_launch(void* const* d_in, const int* in_sizes, int n_in,
                              void* d_out, int out_size, void* d_ws, size_t ws_size,
                              hipStream_t stream) {
    (void)in_sizes; (void)n_in; (void)out_size;
    const int*   input  = (const int*)  d_in[0];
    const float* hidden = (const float*)d_in[2];
    const float* emb    = (const float*)d_in[3];
    const float* W_ih   = (const float*)d_in[4];
    const float* W_hh   = (const float*)d_in[5];
    const float* b_ih   = (const float*)d_in[6];
    const float* b_hh   = (const float*)d_in[7];
    float* out = (float*)d_out;

    // workspace layout (bytes)
    const size_t EMB_BF  = 0;                                   // 65,536,000
    const size_t WIH_BF  = EMB_BF + (size_t)VOCAB * EMBD * 2;   // +6,291,456
    const size_t GI_OFF  = WIH_BF + (size_t)N3H * EMBD * 2;     // +201,326,592
    const size_t H_OFF   = GI_OFF + (size_t)SEQ * BATCH * N3H * 2;
    const size_t FLG_OFF = H_OFF + (size_t)2 * BATCH * HID * 2;
    const size_t NEED    = FLG_OFF + (size_t)NBLK * FLAGSTRIDE * 4;
    if (ws_size < NEED) return;

    char* ws = (char*)d_ws;
    unsigned short* embb = (unsigned short*)(ws + EMB_BF);
    unsigned short* wihb = (unsigned short*)(ws + WIH_BF);
    unsigned short* gib  = (unsigned short*)(ws + GI_OFF);
    unsigned short* hbuf = (unsigned short*)(ws + H_OFF);
    int*            flags = (int*)(ws + FLG_OFF);

    hipMemsetAsync(flags, 0, (size_t)NBLK * FLAGSTRIDE * 4, stream);

    {
        int n4 = VOCAB * EMBD / 4;
        k_cvt4<<<(n4 + 255) / 256, 256, 0, stream>>>((const float4*)emb, (ushort4*)embb, n4);
    }
    {
        int n4 = N3H * EMBD / 4;
        k_cvt4<<<(n4 + 255) / 256, 256, 0, stream>>>((const float4*)W_ih, (ushort4*)wihb, n4);
    }

    // input-side GEMM for all timesteps
    k_gi<<<dim3(48, 128), 256, 0, stream>>>(input, embb, wihb, gib);

    // persistent recurrence: 64 blocks (64 KB LDS each -> all co-resident)
    k_rec<<<NBLK, 256, 0, stream>>>(W_hh, gib, b_ih, b_hh, hidden, out, hbuf, flags);
}